// Round 3
// baseline (242.155 us; speedup 1.0000x reference)
//
#include <hip/hip_runtime.h>

typedef unsigned short u16;
typedef __bf16 bf16x8 __attribute__((ext_vector_type(8)));
typedef float f32x4 __attribute__((ext_vector_type(4)));

// fp32 -> bf16 bits, round-to-nearest-even (finite inputs only)
__device__ __forceinline__ u16 f2bf(float f) {
  union { float f; unsigned u; } v; v.f = f;
  return (u16)((v.u + 0x7fffu + ((v.u >> 16) & 1u)) >> 16);
}
__device__ __forceinline__ float bf2f(u16 h) {
  union { unsigned u; float f; } v; v.u = ((unsigned)h) << 16;
  return v.f;
}

// pack two fp32 -> bf16x2 dword (round-half-up), low = lo, high = hi
__device__ __forceinline__ unsigned pkbf(float lo, float hi) {
  union { float f; unsigned u; } a, b; a.f = lo; b.f = hi;
  return __builtin_amdgcn_perm(b.u + 0x8000u, a.u + 0x8000u, 0x07060302u);
}

__device__ __forceinline__ float fexp2(float x) {
#if __has_builtin(__builtin_amdgcn_exp2f)
  return __builtin_amdgcn_exp2f(x);
#else
  return exp2f(x);
#endif
}

// async global->LDS, 16B per lane; LDS dst = base + lane*16 (wave-uniform base)
__device__ __forceinline__ void gld16(const u16* g, u16* l) {
  __builtin_amdgcn_global_load_lds(
      (const __attribute__((address_space(1))) void*)g,
      (__attribute__((address_space(3))) void*)l, 16, 0, 0);
}

// pi permutation of a key k in [0,64) -> position in vT 64-block / P^T k-slot:
// pos = (k&32) + ((k>>2)&3)*8 + ((k>>4)&1)*4 + (k&3)

// ---------------------------------------------------------------------------
// fp32 -> bf16 bulk convert for all three inputs in ONE dispatch.
// ---------------------------------------------------------------------------
__global__ __launch_bounds__(256) void cvt3(
    const float* __restrict__ x, const float* __restrict__ wa,
    const float* __restrict__ wp, u16* __restrict__ xb,
    u16* __restrict__ wab, u16* __restrict__ wpb)
{
  int b = blockIdx.x;
  const float* in; u16* out; int i;
  if (b < 2048)      { in = x;  out = xb;  i = b * 256 + threadIdx.x; }
  else if (b < 3584) { in = wa; out = wab; i = (b - 2048) * 256 + threadIdx.x; }
  else               { in = wp; out = wpb; i = (b - 3584) * 256 + threadIdx.x; }
  const float* p = in + (size_t)i * 8;
  float4 a = *(const float4*)p, c = *(const float4*)(p + 4);
  uint4 o;
  o.x = pkbf(a.x, a.y); o.y = pkbf(a.z, a.w);
  o.z = pkbf(c.x, c.y); o.w = pkbf(c.z, c.w);
  *(uint4*)&out[(size_t)i * 8] = o;
}

// ---------------------------------------------------------------------------
// combine: y = (O0 + O1) / (l0 + l1).  O* are bf16 unnormalized partials
// [4096][1024]; l* are fp32 [4096][16] (per row,head). 8 elems/thread.
// ---------------------------------------------------------------------------
__global__ __launch_bounds__(256) void combine2(
    const u16* __restrict__ O0, const u16* __restrict__ O1,
    const float* __restrict__ l0, const float* __restrict__ l1,
    u16* __restrict__ y)
{
  int i = blockIdx.x * 256 + threadIdx.x;          // 524288 threads
  int e0 = i * 8;
  int row = e0 >> 10, h = (e0 & 1023) >> 6;
  float inv = 1.0f / (l0[row * 16 + h] + l1[row * 16 + h]);
  uint4 a = *(const uint4*)&O0[(size_t)e0];
  uint4 b = *(const uint4*)&O1[(size_t)e0];
  unsigned aw[4] = {a.x, a.y, a.z, a.w}, bw[4] = {b.x, b.y, b.z, b.w};
  uint4 o;
  unsigned ow[4];
#pragma unroll
  for (int j = 0; j < 4; ++j) {
    float lo = (bf2f((u16)(aw[j] & 0xffffu)) + bf2f((u16)(bw[j] & 0xffffu))) * inv;
    float hi = (bf2f((u16)(aw[j] >> 16))     + bf2f((u16)(bw[j] >> 16)))     * inv;
    ow[j] = pkbf(lo, hi);
  }
  o.x = ow[0]; o.y = ow[1]; o.z = ow[2]; o.w = ow[3];
  *(uint4*)&y[(size_t)e0] = o;
}

// ---------------------------------------------------------------------------
// m97-style GEMM: C[M,N] = A[M,K]*B[N,K]^T, bf16 in, fp32 acc.
// VSPLIT: n0>=2048 blocks write V TRANSPOSED to C2 (vT[1024][4096]) in
// pi-permuted key order.
// ---------------------------------------------------------------------------
template<bool COUT_F32, bool VSPLIT>
__global__ __launch_bounds__(256, 3) void gemm_lds(
    const u16* __restrict__ A, const u16* __restrict__ B, void* __restrict__ C,
    u16* __restrict__ C2, int M, int N, int K, int ldc)
{
  __shared__ u16 S[9216];
  u16* As = S;
  u16* Bs = S + 4096;
  const int tid  = threadIdx.x;
  const int wave = tid >> 6, lane = tid & 63;
  const int quad = lane >> 4, ln = lane & 15;
  const int m0 = blockIdx.y * 128, n0 = blockIdx.x * 128;
  const int wm = (wave >> 1) * 64, wn = (wave & 1) * 64;

  const int srow = wave * 32 + (lane >> 2);
  const int scol = (lane & 3) * 8;

  f32x4 acc[4][4] = {};

  for (int k0 = 0; k0 < K; k0 += 32) {
    __syncthreads();
    const u16* ga = A + (size_t)(m0 + srow) * K + k0 + scol;
    const u16* gb = B + (size_t)(n0 + srow) * K + k0 + scol;
    gld16(ga,                  As + wave * 1024);
    gld16(ga + (size_t)16 * K, As + wave * 1024 + 512);
    gld16(gb,                  Bs + wave * 1024);
    gld16(gb + (size_t)16 * K, Bs + wave * 1024 + 512);
    __syncthreads();

    bf16x8 af[4], bfr[4];
#pragma unroll
    for (int i = 0; i < 4; ++i) af[i]  = *(const bf16x8*)&As[(wm + i * 16 + ln) * 32 + quad * 8];
#pragma unroll
    for (int j = 0; j < 4; ++j) bfr[j] = *(const bf16x8*)&Bs[(wn + j * 16 + ln) * 32 + quad * 8];
#pragma unroll
    for (int i = 0; i < 4; ++i)
#pragma unroll
      for (int j = 0; j < 4; ++j)
        acc[i][j] = __builtin_amdgcn_mfma_f32_16x16x32_bf16(af[i], bfr[j], acc[i][j], 0, 0, 0);
  }

  if constexpr (VSPLIT) {
    if (n0 >= 2048) {
      u16 (*Cs)[72] = (u16(*)[72])S;
      __syncthreads();
#pragma unroll
      for (int c = 0; c < 2; ++c) {
        if ((wave >> 1) == c) {
#pragma unroll
          for (int i = 0; i < 4; ++i)
#pragma unroll
            for (int j = 0; j < 4; ++j)
#pragma unroll
              for (int r = 0; r < 4; ++r) {
                int pos = (i >> 1) * 32 + quad * 8 + (i & 1) * 4 + r;  // pi(m-in-chunk)
                Cs[wn + j * 16 + ln][pos] = f2bf(acc[i][j][r]);
              }
        }
        __syncthreads();
        {
          int nl = tid >> 1, mseg = (tid & 1) * 32;
#pragma unroll
          for (int s2 = 0; s2 < 4; ++s2) {
            uint4 v4 = *(const uint4*)&Cs[nl][mseg + s2 * 8];
            *(uint4*)&C2[(size_t)(n0 - 2048 + nl) * 4096 + m0 + c * 64 + mseg + s2 * 8] = v4;
          }
        }
        __syncthreads();
      }
      return;
    }
  }

#pragma unroll
  for (int i = 0; i < 4; ++i)
#pragma unroll
    for (int j = 0; j < 4; ++j)
#pragma unroll
      for (int r = 0; r < 4; ++r) {
        int m = m0 + wm + i * 16 + quad * 4 + r;   // C/D: row = quad*4+reg
        int n = n0 + wn + j * 16 + ln;             //      col = lane&15
        if constexpr (COUT_F32)
          ((float*)C)[(size_t)m * ldc + n] = acc[i][j][r];
        else
          ((u16*)C)[(size_t)m * ldc + n] = f2bf(acc[i][j][r]);
      }
}

// ---------------------------------------------------------------------------
// 64x64-tile GEMM for GEMM2 (latency-bound -> 4 blocks/CU).
// ---------------------------------------------------------------------------
template<bool COUT_F32>
__global__ __launch_bounds__(256, 4) void gemm_t64(
    const u16* __restrict__ A, const u16* __restrict__ B, void* __restrict__ C,
    int M, int N, int K, int ldc)
{
  __shared__ u16 S[4096];            // As[64][32]@0, Bs[64][32]@2048
  u16* As = S;
  u16* Bs = S + 2048;
  const int tid  = threadIdx.x;
  const int wave = tid >> 6, lane = tid & 63;
  const int quad = lane >> 4, ln = lane & 15;
  const int m0 = blockIdx.y * 64, n0 = blockIdx.x * 64;

  const int srow = wave * 16 + (lane >> 2);
  const int scol = (lane & 3) * 8;

  f32x4 acc[4] = {};

  for (int k0 = 0; k0 < K; k0 += 32) {
    __syncthreads();
    gld16(A + (size_t)(m0 + srow) * K + k0 + scol, As + wave * 512);
    gld16(B + (size_t)(n0 + srow) * K + k0 + scol, Bs + wave * 512);
    __syncthreads();

    bf16x8 af = *(const bf16x8*)&As[(wave * 16 + ln) * 32 + quad * 8];
#pragma unroll
    for (int j = 0; j < 4; ++j) {
      bf16x8 bf = *(const bf16x8*)&Bs[(j * 16 + ln) * 32 + quad * 8];
      acc[j] = __builtin_amdgcn_mfma_f32_16x16x32_bf16(af, bf, acc[j], 0, 0, 0);
    }
  }

#pragma unroll
  for (int j = 0; j < 4; ++j)
#pragma unroll
    for (int r = 0; r < 4; ++r) {
      int m = m0 + wave * 16 + quad * 4 + r;
      int n = n0 + j * 16 + ln;
      if constexpr (COUT_F32)
        ((float*)C)[(size_t)m * ldc + n] = acc[j][r];
      else
        ((u16*)C)[(size_t)m * ldc + n] = f2bf(acc[j][r]);
    }
}

// ---------------------------------------------------------------------------
// Fallback GEMM (fp32 staging) — used only if ws_size < 40 MiB.
// ---------------------------------------------------------------------------
template<bool F32>
__device__ __forceinline__ void stage8(u16* dst, const void* base, size_t off) {
  if constexpr (F32) {
    const float* p = (const float*)base + off;
    float4 a = *(const float4*)p;
    float4 b = *(const float4*)(p + 4);
    uint4 q;
    q.x = pkbf(a.x, a.y); q.y = pkbf(a.z, a.w);
    q.z = pkbf(b.x, b.y); q.w = pkbf(b.z, b.w);
    *(uint4*)dst = q;
  } else {
    *(uint4*)dst = *(const uint4*)((const u16*)base + off);
  }
}

template<bool AF32, bool BF32, bool COUT_F32, bool VSPLIT>
__global__ __launch_bounds__(256) void gemm_bt(
    const void* __restrict__ A, const void* __restrict__ B, void* __restrict__ C,
    u16* __restrict__ C2, int M, int N, int K, int ldc)
{
  __shared__ u16 As[128][40];
  __shared__ u16 Bs[128][40];
  const int tid  = threadIdx.x;
  const int wave = tid >> 6, lane = tid & 63;
  const int quad = lane >> 4, ln = lane & 15;
  const int m0 = blockIdx.y * 128, n0 = blockIdx.x * 128;
  const int wm = (wave >> 1) * 64, wn = (wave & 1) * 64;

  f32x4 acc[4][4] = {};

  for (int k0 = 0; k0 < K; k0 += 32) {
    __syncthreads();
#pragma unroll
    for (int i = 0; i < 2; ++i) {
      int idx = tid + i * 256;
      int row = idx >> 2, seg = (idx & 3) * 8;
      stage8<AF32>(&As[row][seg], A, (size_t)(m0 + row) * K + k0 + seg);
      stage8<BF32>(&Bs[row][seg], B, (size_t)(n0 + row) * K + k0 + seg);
    }
    __syncthreads();
    bf16x8 af[4], bfr[4];
#pragma unroll
    for (int i = 0; i < 4; ++i) af[i]  = *(const bf16x8*)&As[wm + i * 16 + ln][quad * 8];
#pragma unroll
    for (int j = 0; j < 4; ++j) bfr[j] = *(const bf16x8*)&Bs[wn + j * 16 + ln][quad * 8];
#pragma unroll
    for (int i = 0; i < 4; ++i)
#pragma unroll
      for (int j = 0; j < 4; ++j)
        acc[i][j] = __builtin_amdgcn_mfma_f32_16x16x32_bf16(af[i], bfr[j], acc[i][j], 0, 0, 0);
  }

  if constexpr (VSPLIT) {
    if (n0 >= 2048) {
      __shared__ u16 Cs[128][72];
#pragma unroll
      for (int c = 0; c < 2; ++c) {
        if ((wave >> 1) == c) {
#pragma unroll
          for (int i = 0; i < 4; ++i)
#pragma unroll
            for (int j = 0; j < 4; ++j)
#pragma unroll
              for (int r = 0; r < 4; ++r) {
                int pos = (i >> 1) * 32 + quad * 8 + (i & 1) * 4 + r;
                Cs[wn + j * 16 + ln][pos] = f2bf(acc[i][j][r]);
              }
        }
        __syncthreads();
        {
          int nl = tid >> 1, mseg = (tid & 1) * 32;
#pragma unroll
          for (int s2 = 0; s2 < 4; ++s2) {
            uint4 v4 = *(const uint4*)&Cs[nl][mseg + s2 * 8];
            *(uint4*)&C2[(size_t)(n0 - 2048 + nl) * 4096 + m0 + c * 64 + mseg + s2 * 8] = v4;
          }
        }
        __syncthreads();
      }
      return;
    }
  }

#pragma unroll
  for (int i = 0; i < 4; ++i)
#pragma unroll
    for (int j = 0; j < 4; ++j)
#pragma unroll
      for (int r = 0; r < 4; ++r) {
        int m = m0 + wm + i * 16 + quad * 4 + r;
        int n = n0 + wn + j * 16 + ln;
        if constexpr (COUT_F32)
          ((float*)C)[(size_t)m * ldc + n] = acc[i][j][r];
        else
          ((u16*)C)[(size_t)m * ldc + n] = f2bf(acc[i][j][r]);
      }
}

// ---------------------------------------------------------------------------
// Causal flash attention (MFMA), fixed-base softmax (linearly decomposable),
// transposed score path (S^T = K·Q^T, in-register P^T B-frag, O^T = V^T·P^T).
//
// R17 changes vs R16 (which regressed 52.9 -> 62.0 us):
//  * R16 post-mortem: launch_bounds(256,2) CAPPED residency at 2 blocks/CU
//    (8 waves) although the kernel fits 4 (VGPR 80 <= 128, LDS 4x33280 =
//    130 KiB < 160 KiB). Occupancy fell 25 -> 18%, every phase slowed
//    proportionally. Serial 2-job blocks also added a drain boundary per
//    block and lost K/V L2 sharing (FETCH +1.6 GB).
//  * Back to 1024 single-job blocks, launch_bounds(256,4): ALL blocks
//    resident at once (256 CU x 4) -> no refill; the block->CU deal fully
//    determines balance. Both plausible deals (XCD round-robin + per-XCD
//    round-robin/linear) put blocks with equal bx mod 256 on one CU.
//  * Class-balanced mapping: class c = bx&255 (u=c>>4, h=c&15), group
//    g = bx>>8 chooses jobs sized {u+1, 32-u, 17+u, 16-u} -> every class
//    sums to exactly 66 iters (mean). R15's ordering gave 52..80 (~20%
//    structural imbalance; wall tracked 80). Mixed sizes also stagger
//    block completion -> smoother occupancy decay.
//  * Keep: plane LDS layout (16B rows), ones-MFMA l, cvt_pk P-pack, uint2
//    O-stores, full s2 unroll (80 VGPR at cap 256 -> fits cap 128 clean).
//    Spill tripwire: WRITE_SIZE >> 20.5 MB.
// ---------------------------------------------------------------------------
struct StageRegs { uint4 k0, k1, v0, v1; };

__device__ __forceinline__ StageRegs attn_stage_load(
    const u16* __restrict__ qk, const u16* __restrict__ vT,
    int h, int kbase, int tid) {
  StageRegs s;
  {
    int key = tid >> 2, seg = (tid & 3) * 16;
    const u16* kp = qk + (size_t)(kbase + key) * 2048 + 1024 + h * 64 + seg;
    s.k0 = *(const uint4*)kp;
    s.k1 = *(const uint4*)(kp + 8);
  }
  {
    int kh = tid >> 7, d = (tid >> 1) & 63, sg = (tid & 1) * 16;
    const u16* vp = vT + (size_t)(h * 64 + d) * 4096 + kbase + kh * 32 + sg;
    s.v0 = *(const uint4*)vp;
    s.v1 = *(const uint4*)(vp + 8);
  }
  return s;
}

template<bool SPLIT>
__global__ __launch_bounds__(256, 4) void attn_fwd(
    const u16* __restrict__ qk, const u16* __restrict__ vT,
    u16* __restrict__ out0, u16* __restrict__ out1,
    float* __restrict__ l0buf, float* __restrict__ l1buf)
{
  // plane p = hf*4 + chunk (K: d-chunk within d-half hf; V: pi-slot chunk
  // within key-half). Row stride 16B; plane stride 65*16B (bank-group rotate).
  __shared__ __align__(16) u16 Ks[2][8][65][8];
  __shared__ __align__(16) u16 Vt[2][8][65][8];

  const int tid  = threadIdx.x;
  const int wave = tid >> 6, lane = tid & 63;
  const int quad = lane >> 4, ln = lane & 15;
  const int bx = blockIdx.x;
  int qt, h, ktb, kte;
  u16* oout; float* lout;
  if constexpr (SPLIT) {
    // class-balanced deal: per class (u,h), groups g=0..3 give job sizes
    // {u+1, 32-u, 17+u, 16-u} summing to 66 for every class.
    int g = bx >> 8, c = bx & 255, u = c >> 4;
    h = c & 15;
    int half;
    if      (g == 0) { qt = u;      half = 0; }
    else if (g == 1) { qt = 31 - u; half = 1; }
    else if (g == 2) { qt = 16 + u; half = 0; }
    else             { qt = 15 - u; half = 1; }
    ktb = half ? (qt + 1) : 0;
    kte = half ? (2 * qt + 1) : qt;
    oout = half ? out1 : out0;
    lout = half ? l1buf : l0buf;
  } else {
    qt = (bx < 256) ? (31 - (bx >> 4)) : ((bx - 256) >> 4);
    h = bx & 15;
    ktb = 0; kte = 2 * qt + 1;
    oout = out0; lout = nullptr;
  }
  const float C1 = 0.18033688f;        // 0.125 * log2(e)

  const int sq0[2] = { qt * 128 + wave * 32, qt * 128 + wave * 32 + 16 };

  bf16x8 qa[2][2];
#pragma unroll
  for (int s = 0; s < 2; ++s) {
    const u16* qrow = qk + (size_t)(sq0[s] + ln) * 2048 + h * 64;
    qa[s][0] = *(const bf16x8*)(qrow + quad * 8);
    qa[s][1] = *(const bf16x8*)(qrow + 32 + quad * 8);
  }

  bf16x8 ones;
#pragma unroll
  for (int i = 0; i < 8; ++i) ones[i] = (__bf16)1.0f;

  f32x4 o[2][4] = {};                  // O^T tiles: [strip][d-tile]; row=d, col=qrow
  f32x4 la[2] = {};                    // l accumulator (ones-MFMA); every reg = l[ln]

  StageRegs st = attn_stage_load(qk, vT, h, ktb * 64, tid);
  int b = 0;
  for (int kt = ktb; kt <= kte; ++kt, b ^= 1) {
    {
      int key = tid >> 2, seg = (tid & 3) * 16;
      int hf = seg >> 5, q0 = (seg & 31) >> 3;           // q0 in {0,2}
      *(uint4*)&Ks[b][hf * 4 + q0][key][0]     = st.k0;  // d elems seg..seg+7
      *(uint4*)&Ks[b][hf * 4 + q0 + 1][key][0] = st.k1;  // d elems seg+8..seg+15
      int vh = tid >> 7, d = (tid >> 1) & 63, sq = (tid & 1) * 2;  // slot in {0,2}
      *(uint4*)&Vt[b][vh * 4 + sq][d][0]     = st.v0;
      *(uint4*)&Vt[b][vh * 4 + sq + 1][d][0] = st.v1;
    }
    __syncthreads();
    if (kt < kte) st = attn_stage_load(qk, vT, h, (kt + 1) * 64, tid);

    bool act[2];
#pragma unroll
    for (int s = 0; s < 2; ++s) act[s] = (kt * 64 <= sq0[s] + 15);

    // two 32-key subtiles; fully unrolled
#pragma unroll
    for (int s2 = 0; s2 < 2; ++s2) {
      bf16x8 kf[2][2], vb[4];
#pragma unroll
      for (int hf = 0; hf < 2; ++hf)
#pragma unroll
        for (int tp = 0; tp < 2; ++tp)
          kf[hf][tp] = *(const bf16x8*)&Ks[b][hf * 4 + quad][(s2 * 2 + tp) * 16 + ln][0];
#pragma unroll
      for (int dt = 0; dt < 4; ++dt)
        vb[dt] = *(const bf16x8*)&Vt[b][s2 * 4 + quad][dt * 16 + ln][0];

#pragma unroll
      for (int s = 0; s < 2; ++s) {
        if (!act[s]) continue;         // wave-uniform
        f32x4 sv[2];
#pragma unroll
        for (int tp = 0; tp < 2; ++tp) {
          f32x4 z = {0.f, 0.f, 0.f, 0.f};
          z = __builtin_amdgcn_mfma_f32_16x16x32_bf16(kf[0][tp], qa[s][0], z, 0, 0, 0);
          z = __builtin_amdgcn_mfma_f32_16x16x32_bf16(kf[1][tp], qa[s][1], z, 0, 0, 0);
          sv[tp] = z;                  // row=key=(s2*2+tp)*16+quad*4+r, col=qrow=ln
        }
        float p[2][4];                 // [tp][r]
        if (kt * 64 + 63 > sq0[s]) {   // diagonal region: per-element causal mask
          const int qr = sq0[s] + ln;
#pragma unroll
          for (int tp = 0; tp < 2; ++tp) {
            int keyb = kt * 64 + (s2 * 2 + tp) * 16 + quad * 4;
#pragma unroll
            for (int r = 0; r < 4; ++r) {
              float arg = (keyb + r > qr) ? -200.0f : fmaf(sv[tp][r], C1, -46.0f);
              p[tp][r] = fexp2(arg);
            }
          }
        } else {
#pragma unroll
          for (int tp = 0; tp < 2; ++tp)
#pragma unroll
            for (int r = 0; r < 4; ++r)
              p[tp][r] = fexp2(fmaf(sv[tp][r], C1, -46.0f));
        }
        // P^T B-frag for this key-half (H == s2): slot j<4 -> p[0][j], j>=4 -> p[1][j-4]
        bf16x8 pv;
        pv[0] = (__bf16)p[0][0]; pv[1] = (__bf16)p[0][1];
        pv[2] = (__bf16)p[0][2]; pv[3] = (__bf16)p[0][3];
        pv[4] = (__bf16)p[1][0]; pv[5] = (__bf16)p[1][1];
        pv[6] = (__bf16)p[1][2]; pv[7] = (__bf16)p[1][3];
        // l on the MFMA pipe: D[row][col] = sum_k 1 * P^T[k][col] = l[qcol],
        // replicated over all (quad, r) -> no cross-lane reduce needed.
        la[s] = __builtin_amdgcn_mfma_f32_16x16x32_bf16(ones, pv, la[s], 0, 0, 0);
#pragma unroll
        for (int dt = 0; dt < 4; ++dt)
          o[s][dt] = __builtin_amdgcn_mfma_f32_16x16x32_bf16(vb[dt], pv, o[s][dt], 0, 0, 0);
      }
    }
  }

#pragma unroll
  for (int s = 0; s < 2; ++s) {
    int rowg = sq0[s] + ln;
    float l_s = la[s][0];              // same value in every acc reg / quad
    if constexpr (SPLIT) {
      // unnormalized bf16 partial + fp32 l partial (quad 0 stores l once)
#pragma unroll
      for (int dt = 0; dt < 4; ++dt) {
        uint2 w;
        w.x = pkbf(o[s][dt][0], o[s][dt][1]);
        w.y = pkbf(o[s][dt][2], o[s][dt][3]);
        *(uint2*)&oout[(size_t)rowg * 1024 + h * 64 + dt * 16 + quad * 4] = w;
      }
      if (quad == 0) lout[rowg * 16 + h] = l_s;
    } else {
      float inv = 1.0f / l_s;
#pragma unroll
      for (int dt = 0; dt < 4; ++dt) {
        uint2 w;
        w.x = pkbf(o[s][dt][0] * inv, o[s][dt][1] * inv);
        w.y = pkbf(o[s][dt][2] * inv, o[s][dt][3] * inv);
        *(uint2*)&oout[(size_t)rowg * 1024 + h * 64 + dt * 16 + quad * 4] = w;
      }
    }
  }
}

extern "C" void kernel_launch(void* const* d_in, const int* in_sizes, int n_in,
                              void* d_out, int out_size, void* d_ws, size_t ws_size,
                              hipStream_t stream) {
  const float* x      = (const float*)d_in[0];   // [4096,1024] fp32
  const float* w_attn = (const float*)d_in[1];   // [3072,1024] fp32
  const float* w_proj = (const float*)d_in[2];   // [1024,1024] fp32

  char* ws = (char*)d_ws;
  u16* qk = (u16*)ws;                        // 16 MiB [4096][2048]
  u16* vT = (u16*)(ws + (16u << 20));        //  8 MiB [1024][4096] pi-permuted

  if (ws_size >= (size_t)(44u << 20)) {
    // Path A: key-split attention with partial combine. Peak 42.25 MiB.
    u16*   wpb = (u16*)(ws + (24u << 20));   //  2 MiB bf16 w_proj
    u16*   xb  = (u16*)(ws + (26u << 20));   //  8 MiB bf16 x       (dead after GEMM1)
    u16*   wab = (u16*)(ws + (34u << 20));   //  6 MiB bf16 w_attn  (dead after GEMM1)
    u16*   Op0 = (u16*)(ws + (26u << 20));   //  8 MiB bf16 O-partial half0 (overlays xb)
    u16*   Op1 = (u16*)(ws + (34u << 20));   //  8 MiB bf16 O-partial half1 (overlays wab + 2 MiB)
    float* l0  = (float*)(ws + (42u << 20));            // 256 KiB
    float* l1  = (float*)(ws + (42u << 20) + (256u << 10)); // 256 KiB
    u16*   y   = (u16*)ws;                   //  8 MiB, overlays qk (dead after attn)

    cvt3<<<4096, 256, 0, stream>>>(x, w_attn, w_proj, xb, wab, wpb);
    gemm_lds<false, true><<<dim3(24, 32), 256, 0, stream>>>(
        xb, wab, qk, vT, 4096, 3072, 1024, 2048);
    attn_fwd<true><<<dim3(1024), 256, 0, stream>>>(qk, vT, Op0, Op1, l0, l1);
    combine2<<<2048, 256, 0, stream>>>(Op0, Op1, l0, l1, y);
    gemm_t64<true><<<dim3(16, 64), 256, 0, stream>>>(
        y, wpb, d_out, 4096, 1024, 1024, 1024);
  } else if (ws_size >= (size_t)(40u << 20)) {
    // Path B: R11 behavior.
    u16* wpb = (u16*)(ws + (24u << 20));
    u16* xb  = (u16*)(ws + (26u << 20));
    u16* wab = (u16*)(ws + (34u << 20));
    u16* y   = (u16*)(ws + (26u << 20));

    cvt3<<<4096, 256, 0, stream>>>(x, w_attn, w_proj, xb, wab, wpb);
    gemm_lds<false, true><<<dim3(24, 32), 256, 0, stream>>>(
        xb, wab, qk, vT, 4096, 3072, 1024, 2048);
    attn_fwd<false><<<dim3(512), 256, 0, stream>>>(qk, vT, y, nullptr, nullptr, nullptr);
    gemm_t64<true><<<dim3(16, 64), 256, 0, stream>>>(
        y, wpb, d_out, 4096, 1024, 1024, 1024);
  } else {
    // Path C: fp32-staging fallback.
    u16* y = (u16*)(ws + (24u << 20));
    gemm_bt<true, true, false, true><<<dim3(24, 32), 256, 0, stream>>>(
        x, w_attn, qk, vT, 4096, 3072, 1024, 2048);
    attn_fwd<false><<<dim3(512), 256, 0, stream>>>(qk, vT, y, nullptr, nullptr, nullptr);
    gemm_bt<false, true, true, false><<<dim3(8, 32), 256, 0, stream>>>(
        y, w_proj, d_out, nullptr, 4096, 1024, 1024, 1024);
  }
}

// Round 4
// 192.623 us; speedup vs baseline: 1.2571x; 1.2571x over previous
//
#include <hip/hip_runtime.h>

typedef unsigned short u16;
typedef __bf16 bf16x8 __attribute__((ext_vector_type(8)));
typedef float f32x4 __attribute__((ext_vector_type(4)));

// fp32 -> bf16 bits, round-to-nearest-even (finite inputs only)
__device__ __forceinline__ u16 f2bf(float f) {
  union { float f; unsigned u; } v; v.f = f;
  return (u16)((v.u + 0x7fffu + ((v.u >> 16) & 1u)) >> 16);
}
__device__ __forceinline__ float bf2f(u16 h) {
  union { unsigned u; float f; } v; v.u = ((unsigned)h) << 16;
  return v.f;
}

// pack two fp32 -> bf16x2 dword (round-half-up), low = lo, high = hi
__device__ __forceinline__ unsigned pkbf(float lo, float hi) {
  union { float f; unsigned u; } a, b; a.f = lo; b.f = hi;
  return __builtin_amdgcn_perm(b.u + 0x8000u, a.u + 0x8000u, 0x07060302u);
}

__device__ __forceinline__ float fexp2(float x) {
#if __has_builtin(__builtin_amdgcn_exp2f)
  return __builtin_amdgcn_exp2f(x);
#else
  return exp2f(x);
#endif
}

// async global->LDS, 16B per lane; LDS dst = base + lane*16 (wave-uniform base)
__device__ __forceinline__ void gld16(const u16* g, u16* l) {
  __builtin_amdgcn_global_load_lds(
      (const __attribute__((address_space(1))) void*)g,
      (__attribute__((address_space(3))) void*)l, 16, 0, 0);
}

// pi permutation of a key k in [0,64) -> position in vT 64-block / P^T k-slot:
// pos = (k&32) + ((k>>2)&3)*8 + ((k>>4)&1)*4 + (k&3)

// ---------------------------------------------------------------------------
// fp32 -> bf16 bulk convert for all three inputs in ONE dispatch.
// ---------------------------------------------------------------------------
__global__ __launch_bounds__(256) void cvt3(
    const float* __restrict__ x, const float* __restrict__ wa,
    const float* __restrict__ wp, u16* __restrict__ xb,
    u16* __restrict__ wab, u16* __restrict__ wpb)
{
  int b = blockIdx.x;
  const float* in; u16* out; int i;
  if (b < 2048)      { in = x;  out = xb;  i = b * 256 + threadIdx.x; }
  else if (b < 3584) { in = wa; out = wab; i = (b - 2048) * 256 + threadIdx.x; }
  else               { in = wp; out = wpb; i = (b - 3584) * 256 + threadIdx.x; }
  const float* p = in + (size_t)i * 8;
  float4 a = *(const float4*)p, c = *(const float4*)(p + 4);
  uint4 o;
  o.x = pkbf(a.x, a.y); o.y = pkbf(a.z, a.w);
  o.z = pkbf(c.x, c.y); o.w = pkbf(c.z, c.w);
  *(uint4*)&out[(size_t)i * 8] = o;
}

// ---------------------------------------------------------------------------
// combine: y = (O0 + O1) / (l0 + l1).  O* are bf16 unnormalized partials
// [4096][1024]; l* are fp32 [4096][16] (per row,head). 8 elems/thread.
// ---------------------------------------------------------------------------
__global__ __launch_bounds__(256) void combine2(
    const u16* __restrict__ O0, const u16* __restrict__ O1,
    const float* __restrict__ l0, const float* __restrict__ l1,
    u16* __restrict__ y)
{
  int i = blockIdx.x * 256 + threadIdx.x;          // 524288 threads
  int e0 = i * 8;
  int row = e0 >> 10, h = (e0 & 1023) >> 6;
  float inv = 1.0f / (l0[row * 16 + h] + l1[row * 16 + h]);
  uint4 a = *(const uint4*)&O0[(size_t)e0];
  uint4 b = *(const uint4*)&O1[(size_t)e0];
  unsigned aw[4] = {a.x, a.y, a.z, a.w}, bw[4] = {b.x, b.y, b.z, b.w};
  uint4 o;
  unsigned ow[4];
#pragma unroll
  for (int j = 0; j < 4; ++j) {
    float lo = (bf2f((u16)(aw[j] & 0xffffu)) + bf2f((u16)(bw[j] & 0xffffu))) * inv;
    float hi = (bf2f((u16)(aw[j] >> 16))     + bf2f((u16)(bw[j] >> 16)))     * inv;
    ow[j] = pkbf(lo, hi);
  }
  o.x = ow[0]; o.y = ow[1]; o.z = ow[2]; o.w = ow[3];
  *(uint4*)&y[(size_t)e0] = o;
}

// ---------------------------------------------------------------------------
// m97-style GEMM: C[M,N] = A[M,K]*B[N,K]^T, bf16 in, fp32 acc.
// VSPLIT: n0>=2048 blocks write V TRANSPOSED to C2 (vT[1024][4096]) in
// pi-permuted key order.
// ---------------------------------------------------------------------------
template<bool COUT_F32, bool VSPLIT>
__global__ __launch_bounds__(256, 3) void gemm_lds(
    const u16* __restrict__ A, const u16* __restrict__ B, void* __restrict__ C,
    u16* __restrict__ C2, int M, int N, int K, int ldc)
{
  __shared__ u16 S[9216];
  u16* As = S;
  u16* Bs = S + 4096;
  const int tid  = threadIdx.x;
  const int wave = tid >> 6, lane = tid & 63;
  const int quad = lane >> 4, ln = lane & 15;
  const int m0 = blockIdx.y * 128, n0 = blockIdx.x * 128;
  const int wm = (wave >> 1) * 64, wn = (wave & 1) * 64;

  const int srow = wave * 32 + (lane >> 2);
  const int scol = (lane & 3) * 8;

  f32x4 acc[4][4] = {};

  for (int k0 = 0; k0 < K; k0 += 32) {
    __syncthreads();
    const u16* ga = A + (size_t)(m0 + srow) * K + k0 + scol;
    const u16* gb = B + (size_t)(n0 + srow) * K + k0 + scol;
    gld16(ga,                  As + wave * 1024);
    gld16(ga + (size_t)16 * K, As + wave * 1024 + 512);
    gld16(gb,                  Bs + wave * 1024);
    gld16(gb + (size_t)16 * K, Bs + wave * 1024 + 512);
    __syncthreads();

    bf16x8 af[4], bfr[4];
#pragma unroll
    for (int i = 0; i < 4; ++i) af[i]  = *(const bf16x8*)&As[(wm + i * 16 + ln) * 32 + quad * 8];
#pragma unroll
    for (int j = 0; j < 4; ++j) bfr[j] = *(const bf16x8*)&Bs[(wn + j * 16 + ln) * 32 + quad * 8];
#pragma unroll
    for (int i = 0; i < 4; ++i)
#pragma unroll
      for (int j = 0; j < 4; ++j)
        acc[i][j] = __builtin_amdgcn_mfma_f32_16x16x32_bf16(af[i], bfr[j], acc[i][j], 0, 0, 0);
  }

  if constexpr (VSPLIT) {
    if (n0 >= 2048) {
      u16 (*Cs)[72] = (u16(*)[72])S;
      __syncthreads();
#pragma unroll
      for (int c = 0; c < 2; ++c) {
        if ((wave >> 1) == c) {
#pragma unroll
          for (int i = 0; i < 4; ++i)
#pragma unroll
            for (int j = 0; j < 4; ++j)
#pragma unroll
              for (int r = 0; r < 4; ++r) {
                int pos = (i >> 1) * 32 + quad * 8 + (i & 1) * 4 + r;  // pi(m-in-chunk)
                Cs[wn + j * 16 + ln][pos] = f2bf(acc[i][j][r]);
              }
        }
        __syncthreads();
        {
          int nl = tid >> 1, mseg = (tid & 1) * 32;
#pragma unroll
          for (int s2 = 0; s2 < 4; ++s2) {
            uint4 v4 = *(const uint4*)&Cs[nl][mseg + s2 * 8];
            *(uint4*)&C2[(size_t)(n0 - 2048 + nl) * 4096 + m0 + c * 64 + mseg + s2 * 8] = v4;
          }
        }
        __syncthreads();
      }
      return;
    }
  }

#pragma unroll
  for (int i = 0; i < 4; ++i)
#pragma unroll
    for (int j = 0; j < 4; ++j)
#pragma unroll
      for (int r = 0; r < 4; ++r) {
        int m = m0 + wm + i * 16 + quad * 4 + r;   // C/D: row = quad*4+reg
        int n = n0 + wn + j * 16 + ln;             //      col = lane&15
        if constexpr (COUT_F32)
          ((float*)C)[(size_t)m * ldc + n] = acc[i][j][r];
        else
          ((u16*)C)[(size_t)m * ldc + n] = f2bf(acc[i][j][r]);
      }
}

// ---------------------------------------------------------------------------
// 64x64-tile GEMM for GEMM2 (latency-bound -> 4 blocks/CU).
// ---------------------------------------------------------------------------
template<bool COUT_F32>
__global__ __launch_bounds__(256, 4) void gemm_t64(
    const u16* __restrict__ A, const u16* __restrict__ B, void* __restrict__ C,
    int M, int N, int K, int ldc)
{
  __shared__ u16 S[4096];            // As[64][32]@0, Bs[64][32]@2048
  u16* As = S;
  u16* Bs = S + 2048;
  const int tid  = threadIdx.x;
  const int wave = tid >> 6, lane = tid & 63;
  const int quad = lane >> 4, ln = lane & 15;
  const int m0 = blockIdx.y * 64, n0 = blockIdx.x * 64;

  const int srow = wave * 16 + (lane >> 2);
  const int scol = (lane & 3) * 8;

  f32x4 acc[4] = {};

  for (int k0 = 0; k0 < K; k0 += 32) {
    __syncthreads();
    gld16(A + (size_t)(m0 + srow) * K + k0 + scol, As + wave * 512);
    gld16(B + (size_t)(n0 + srow) * K + k0 + scol, Bs + wave * 512);
    __syncthreads();

    bf16x8 af = *(const bf16x8*)&As[(wave * 16 + ln) * 32 + quad * 8];
#pragma unroll
    for (int j = 0; j < 4; ++j) {
      bf16x8 bf = *(const bf16x8*)&Bs[(j * 16 + ln) * 32 + quad * 8];
      acc[j] = __builtin_amdgcn_mfma_f32_16x16x32_bf16(af, bf, acc[j], 0, 0, 0);
    }
  }

#pragma unroll
  for (int j = 0; j < 4; ++j)
#pragma unroll
    for (int r = 0; r < 4; ++r) {
      int m = m0 + wave * 16 + quad * 4 + r;
      int n = n0 + j * 16 + ln;
      if constexpr (COUT_F32)
        ((float*)C)[(size_t)m * ldc + n] = acc[j][r];
      else
        ((u16*)C)[(size_t)m * ldc + n] = f2bf(acc[j][r]);
    }
}

// ---------------------------------------------------------------------------
// Fallback GEMM (fp32 staging) — used only if ws_size < 40 MiB.
// ---------------------------------------------------------------------------
template<bool F32>
__device__ __forceinline__ void stage8(u16* dst, const void* base, size_t off) {
  if constexpr (F32) {
    const float* p = (const float*)base + off;
    float4 a = *(const float4*)p;
    float4 b = *(const float4*)(p + 4);
    uint4 q;
    q.x = pkbf(a.x, a.y); q.y = pkbf(a.z, a.w);
    q.z = pkbf(b.x, b.y); q.w = pkbf(b.z, b.w);
    *(uint4*)dst = q;
  } else {
    *(uint4*)dst = *(const uint4*)((const u16*)base + off);
  }
}

template<bool AF32, bool BF32, bool COUT_F32, bool VSPLIT>
__global__ __launch_bounds__(256) void gemm_bt(
    const void* __restrict__ A, const void* __restrict__ B, void* __restrict__ C,
    u16* __restrict__ C2, int M, int N, int K, int ldc)
{
  __shared__ u16 As[128][40];
  __shared__ u16 Bs[128][40];
  const int tid  = threadIdx.x;
  const int wave = tid >> 6, lane = tid & 63;
  const int quad = lane >> 4, ln = lane & 15;
  const int m0 = blockIdx.y * 128, n0 = blockIdx.x * 128;
  const int wm = (wave >> 1) * 64, wn = (wave & 1) * 64;

  f32x4 acc[4][4] = {};

  for (int k0 = 0; k0 < K; k0 += 32) {
    __syncthreads();
#pragma unroll
    for (int i = 0; i < 2; ++i) {
      int idx = tid + i * 256;
      int row = idx >> 2, seg = (idx & 3) * 8;
      stage8<AF32>(&As[row][seg], A, (size_t)(m0 + row) * K + k0 + seg);
      stage8<BF32>(&Bs[row][seg], B, (size_t)(n0 + row) * K + k0 + seg);
    }
    __syncthreads();
    bf16x8 af[4], bfr[4];
#pragma unroll
    for (int i = 0; i < 4; ++i) af[i]  = *(const bf16x8*)&As[wm + i * 16 + ln][quad * 8];
#pragma unroll
    for (int j = 0; j < 4; ++j) bfr[j] = *(const bf16x8*)&Bs[wn + j * 16 + ln][quad * 8];
#pragma unroll
    for (int i = 0; i < 4; ++i)
#pragma unroll
      for (int j = 0; j < 4; ++j)
        acc[i][j] = __builtin_amdgcn_mfma_f32_16x16x32_bf16(af[i], bfr[j], acc[i][j], 0, 0, 0);
  }

  if constexpr (VSPLIT) {
    if (n0 >= 2048) {
      __shared__ u16 Cs[128][72];
#pragma unroll
      for (int c = 0; c < 2; ++c) {
        if ((wave >> 1) == c) {
#pragma unroll
          for (int i = 0; i < 4; ++i)
#pragma unroll
            for (int j = 0; j < 4; ++j)
#pragma unroll
              for (int r = 0; r < 4; ++r) {
                int pos = (i >> 1) * 32 + quad * 8 + (i & 1) * 4 + r;
                Cs[wn + j * 16 + ln][pos] = f2bf(acc[i][j][r]);
              }
        }
        __syncthreads();
        {
          int nl = tid >> 1, mseg = (tid & 1) * 32;
#pragma unroll
          for (int s2 = 0; s2 < 4; ++s2) {
            uint4 v4 = *(const uint4*)&Cs[nl][mseg + s2 * 8];
            *(uint4*)&C2[(size_t)(n0 - 2048 + nl) * 4096 + m0 + c * 64 + mseg + s2 * 8] = v4;
          }
        }
        __syncthreads();
      }
      return;
    }
  }

#pragma unroll
  for (int i = 0; i < 4; ++i)
#pragma unroll
    for (int j = 0; j < 4; ++j)
#pragma unroll
      for (int r = 0; r < 4; ++r) {
        int m = m0 + wm + i * 16 + quad * 4 + r;
        int n = n0 + wn + j * 16 + ln;
        if constexpr (COUT_F32)
          ((float*)C)[(size_t)m * ldc + n] = acc[i][j][r];
        else
          ((u16*)C)[(size_t)m * ldc + n] = f2bf(acc[i][j][r]);
      }
}

// ---------------------------------------------------------------------------
// Causal flash attention (MFMA), fixed-base softmax (linearly decomposable),
// transposed score path (S^T = K·Q^T, in-register P^T B-frag, O^T = V^T·P^T).
//
// R18 = R15 body (proven 52.9 us: launch_bounds(256,3) + '#pragma unroll 1'
// register diet, VGPR 76, WRITE 20.5 MB no-spill) + class-balanced mapping.
//  * R16 lesson: (256,2) caps residency below capacity -> 18% occ, slow.
//  * R17 lesson: (256,4) caps VGPR at 128 -> massive spill (WRITE 125 MB,
//    FETCH +17 GB, 111 us). Body needs ~170 unified regs with the diet;
//    (256,3) is the only clean point. DO NOT TOUCH launch_bounds/unroll.
//  * Class-balanced mapping (kept from R17, the one good idea): block->CU
//    deal groups blocks by bx mod 256 (XCD round-robin + per-XCD rr). Class
//    c (u=c>>4, h=c&15), group g=bx>>8 -> job sizes {u+1, 32-u, 17+u, 16-u}
//    = 66 iters per class exactly (R15's mapping gave 52..80; wall ~80).
//    Refill self-balances: class-u CUs free first slot at t~u+1 (monotone),
//    g3 jobs arrive in descending size 16-u' -> earliest-freeing CU takes
//    the largest refill; every CU totals 66.
// ---------------------------------------------------------------------------
struct StageRegs { uint4 k0, k1, v0, v1; };

__device__ __forceinline__ StageRegs attn_stage_load(
    const u16* __restrict__ qk, const u16* __restrict__ vT,
    int h, int kbase, int tid) {
  StageRegs s;
  {
    int key = tid >> 2, seg = (tid & 3) * 16;
    const u16* kp = qk + (size_t)(kbase + key) * 2048 + 1024 + h * 64 + seg;
    s.k0 = *(const uint4*)kp;
    s.k1 = *(const uint4*)(kp + 8);
  }
  {
    int kh = tid >> 7, d = (tid >> 1) & 63, sg = (tid & 1) * 16;
    const u16* vp = vT + (size_t)(h * 64 + d) * 4096 + kbase + kh * 32 + sg;
    s.v0 = *(const uint4*)vp;
    s.v1 = *(const uint4*)(vp + 8);
  }
  return s;
}

template<bool SPLIT>
__global__ __launch_bounds__(256, SPLIT ? 3 : 2) void attn_fwd(
    const u16* __restrict__ qk, const u16* __restrict__ vT,
    u16* __restrict__ out0, u16* __restrict__ out1,
    float* __restrict__ l0buf, float* __restrict__ l1buf)
{
  // plane p = hf*4 + chunk (K: d-chunk within d-half hf; V: pi-slot chunk
  // within key-half). Row stride 16B; plane stride 65*16B (bank-group rotate).
  __shared__ __align__(16) u16 Ks[2][8][65][8];
  __shared__ __align__(16) u16 Vt[2][8][65][8];

  const int tid  = threadIdx.x;
  const int wave = tid >> 6, lane = tid & 63;
  const int quad = lane >> 4, ln = lane & 15;
  const int bx = blockIdx.x;
  int qt, h, ktb, kte;
  u16* oout; float* lout;
  if constexpr (SPLIT) {
    // class-balanced deal: per class (u,h), groups g=0..3 give job sizes
    // {u+1, 32-u, 17+u, 16-u} summing to 66 for every class.
    int g = bx >> 8, c = bx & 255, u = c >> 4;
    h = c & 15;
    int half;
    if      (g == 0) { qt = u;      half = 0; }
    else if (g == 1) { qt = 31 - u; half = 1; }
    else if (g == 2) { qt = 16 + u; half = 0; }
    else             { qt = 15 - u; half = 1; }
    ktb = half ? (qt + 1) : 0;
    kte = half ? (2 * qt + 1) : qt;
    oout = half ? out1 : out0;
    lout = half ? l1buf : l0buf;
  } else {
    qt = (bx < 256) ? (31 - (bx >> 4)) : ((bx - 256) >> 4);
    h = bx & 15;
    ktb = 0; kte = 2 * qt + 1;
    oout = out0; lout = nullptr;
  }
  const float C1 = 0.18033688f;        // 0.125 * log2(e)

  const int sq0[2] = { qt * 128 + wave * 32, qt * 128 + wave * 32 + 16 };

  bf16x8 qa[2][2];
#pragma unroll
  for (int s = 0; s < 2; ++s) {
    const u16* qrow = qk + (size_t)(sq0[s] + ln) * 2048 + h * 64;
    qa[s][0] = *(const bf16x8*)(qrow + quad * 8);
    qa[s][1] = *(const bf16x8*)(qrow + 32 + quad * 8);
  }

  bf16x8 ones;
#pragma unroll
  for (int i = 0; i < 8; ++i) ones[i] = (__bf16)1.0f;

  f32x4 o[2][4] = {};                  // O^T tiles: [strip][d-tile]; row=d, col=qrow
  f32x4 la[2] = {};                    // l accumulator (ones-MFMA); every reg = l[ln]

  StageRegs st = attn_stage_load(qk, vT, h, ktb * 64, tid);
  int b = 0;
  for (int kt = ktb; kt <= kte; ++kt, b ^= 1) {
    {
      int key = tid >> 2, seg = (tid & 3) * 16;
      int hf = seg >> 5, q0 = (seg & 31) >> 3;           // q0 in {0,2}
      *(uint4*)&Ks[b][hf * 4 + q0][key][0]     = st.k0;  // d elems seg..seg+7
      *(uint4*)&Ks[b][hf * 4 + q0 + 1][key][0] = st.k1;  // d elems seg+8..seg+15
      int vh = tid >> 7, d = (tid >> 1) & 63, sq = (tid & 1) * 2;  // slot in {0,2}
      *(uint4*)&Vt[b][vh * 4 + sq][d][0]     = st.v0;
      *(uint4*)&Vt[b][vh * 4 + sq + 1][d][0] = st.v1;
    }
    __syncthreads();
    if (kt < kte) st = attn_stage_load(qk, vT, h, (kt + 1) * 64, tid);

    bool act[2];
#pragma unroll
    for (int s = 0; s < 2; ++s) act[s] = (kt * 64 <= sq0[s] + 15);

    // two 32-key subtiles, real loop (unroll 1) to bound register pressure
#pragma unroll 1
    for (int s2 = 0; s2 < 2; ++s2) {
      bf16x8 kf[2][2], vb[4];
#pragma unroll
      for (int hf = 0; hf < 2; ++hf)
#pragma unroll
        for (int tp = 0; tp < 2; ++tp)
          kf[hf][tp] = *(const bf16x8*)&Ks[b][hf * 4 + quad][(s2 * 2 + tp) * 16 + ln][0];
#pragma unroll
      for (int dt = 0; dt < 4; ++dt)
        vb[dt] = *(const bf16x8*)&Vt[b][s2 * 4 + quad][dt * 16 + ln][0];

#pragma unroll
      for (int s = 0; s < 2; ++s) {
        if (!act[s]) continue;         // wave-uniform
        f32x4 sv[2];
#pragma unroll
        for (int tp = 0; tp < 2; ++tp) {
          f32x4 z = {0.f, 0.f, 0.f, 0.f};
          z = __builtin_amdgcn_mfma_f32_16x16x32_bf16(kf[0][tp], qa[s][0], z, 0, 0, 0);
          z = __builtin_amdgcn_mfma_f32_16x16x32_bf16(kf[1][tp], qa[s][1], z, 0, 0, 0);
          sv[tp] = z;                  // row=key=(s2*2+tp)*16+quad*4+r, col=qrow=ln
        }
        float p[2][4];                 // [tp][r]
        if (kt * 64 + 63 > sq0[s]) {   // diagonal region: per-element causal mask
          const int qr = sq0[s] + ln;
#pragma unroll
          for (int tp = 0; tp < 2; ++tp) {
            int keyb = kt * 64 + (s2 * 2 + tp) * 16 + quad * 4;
#pragma unroll
            for (int r = 0; r < 4; ++r) {
              float arg = (keyb + r > qr) ? -200.0f : fmaf(sv[tp][r], C1, -46.0f);
              p[tp][r] = fexp2(arg);
            }
          }
        } else {
#pragma unroll
          for (int tp = 0; tp < 2; ++tp)
#pragma unroll
            for (int r = 0; r < 4; ++r)
              p[tp][r] = fexp2(fmaf(sv[tp][r], C1, -46.0f));
        }
        // P^T B-frag for this key-half (H == s2): slot j<4 -> p[0][j], j>=4 -> p[1][j-4]
        bf16x8 pv;
        pv[0] = (__bf16)p[0][0]; pv[1] = (__bf16)p[0][1];
        pv[2] = (__bf16)p[0][2]; pv[3] = (__bf16)p[0][3];
        pv[4] = (__bf16)p[1][0]; pv[5] = (__bf16)p[1][1];
        pv[6] = (__bf16)p[1][2]; pv[7] = (__bf16)p[1][3];
        // l on the MFMA pipe: D[row][col] = sum_k 1 * P^T[k][col] = l[qcol],
        // replicated over all (quad, r) -> no cross-lane reduce needed.
        la[s] = __builtin_amdgcn_mfma_f32_16x16x32_bf16(ones, pv, la[s], 0, 0, 0);
#pragma unroll
        for (int dt = 0; dt < 4; ++dt)
          o[s][dt] = __builtin_amdgcn_mfma_f32_16x16x32_bf16(vb[dt], pv, o[s][dt], 0, 0, 0);
      }
    }
  }

#pragma unroll
  for (int s = 0; s < 2; ++s) {
    int rowg = sq0[s] + ln;
    float l_s = la[s][0];              // same value in every acc reg / quad
    if constexpr (SPLIT) {
      // unnormalized bf16 partial + fp32 l partial (quad 0 stores l once)
#pragma unroll
      for (int dt = 0; dt < 4; ++dt) {
        uint2 w;
        w.x = pkbf(o[s][dt][0], o[s][dt][1]);
        w.y = pkbf(o[s][dt][2], o[s][dt][3]);
        *(uint2*)&oout[(size_t)rowg * 1024 + h * 64 + dt * 16 + quad * 4] = w;
      }
      if (quad == 0) lout[rowg * 16 + h] = l_s;
    } else {
      float inv = 1.0f / l_s;
#pragma unroll
      for (int dt = 0; dt < 4; ++dt) {
        uint2 w;
        w.x = pkbf(o[s][dt][0] * inv, o[s][dt][1] * inv);
        w.y = pkbf(o[s][dt][2] * inv, o[s][dt][3] * inv);
        *(uint2*)&oout[(size_t)rowg * 1024 + h * 64 + dt * 16 + quad * 4] = w;
      }
    }
  }
}

extern "C" void kernel_launch(void* const* d_in, const int* in_sizes, int n_in,
                              void* d_out, int out_size, void* d_ws, size_t ws_size,
                              hipStream_t stream) {
  const float* x      = (const float*)d_in[0];   // [4096,1024] fp32
  const float* w_attn = (const float*)d_in[1];   // [3072,1024] fp32
  const float* w_proj = (const float*)d_in[2];   // [1024,1024] fp32

  char* ws = (char*)d_ws;
  u16* qk = (u16*)ws;                        // 16 MiB [4096][2048]
  u16* vT = (u16*)(ws + (16u << 20));        //  8 MiB [1024][4096] pi-permuted

  if (ws_size >= (size_t)(44u << 20)) {
    // Path A: key-split attention with partial combine. Peak 42.25 MiB.
    u16*   wpb = (u16*)(ws + (24u << 20));   //  2 MiB bf16 w_proj
    u16*   xb  = (u16*)(ws + (26u << 20));   //  8 MiB bf16 x       (dead after GEMM1)
    u16*   wab = (u16*)(ws + (34u << 20));   //  6 MiB bf16 w_attn  (dead after GEMM1)
    u16*   Op0 = (u16*)(ws + (26u << 20));   //  8 MiB bf16 O-partial half0 (overlays xb)
    u16*   Op1 = (u16*)(ws + (34u << 20));   //  8 MiB bf16 O-partial half1 (overlays wab + 2 MiB)
    float* l0  = (float*)(ws + (42u << 20));            // 256 KiB
    float* l1  = (float*)(ws + (42u << 20) + (256u << 10)); // 256 KiB
    u16*   y   = (u16*)ws;                   //  8 MiB, overlays qk (dead after attn)

    cvt3<<<4096, 256, 0, stream>>>(x, w_attn, w_proj, xb, wab, wpb);
    gemm_lds<false, true><<<dim3(24, 32), 256, 0, stream>>>(
        xb, wab, qk, vT, 4096, 3072, 1024, 2048);
    attn_fwd<true><<<dim3(1024), 256, 0, stream>>>(qk, vT, Op0, Op1, l0, l1);
    combine2<<<2048, 256, 0, stream>>>(Op0, Op1, l0, l1, y);
    gemm_t64<true><<<dim3(16, 64), 256, 0, stream>>>(
        y, wpb, d_out, 4096, 1024, 1024, 1024);
  } else if (ws_size >= (size_t)(40u << 20)) {
    // Path B: R11 behavior.
    u16* wpb = (u16*)(ws + (24u << 20));
    u16* xb  = (u16*)(ws + (26u << 20));
    u16* wab = (u16*)(ws + (34u << 20));
    u16* y   = (u16*)(ws + (26u << 20));

    cvt3<<<4096, 256, 0, stream>>>(x, w_attn, w_proj, xb, wab, wpb);
    gemm_lds<false, true><<<dim3(24, 32), 256, 0, stream>>>(
        xb, wab, qk, vT, 4096, 3072, 1024, 2048);
    attn_fwd<false><<<dim3(512), 256, 0, stream>>>(qk, vT, y, nullptr, nullptr, nullptr);
    gemm_t64<true><<<dim3(16, 64), 256, 0, stream>>>(
        y, wpb, d_out, 4096, 1024, 1024, 1024);
  } else {
    // Path C: fp32-staging fallback.
    u16* y = (u16*)(ws + (24u << 20));
    gemm_bt<true, true, false, true><<<dim3(24, 32), 256, 0, stream>>>(
        x, w_attn, qk, vT, 4096, 3072, 1024, 2048);
    attn_fwd<false><<<dim3(512), 256, 0, stream>>>(qk, vT, y, nullptr, nullptr, nullptr);
    gemm_bt<false, true, true, false><<<dim3(8, 32), 256, 0, stream>>>(
        y, w_proj, d_out, nullptr, 4096, 1024, 1024, 1024);
  }
}

// Round 5
// 185.811 us; speedup vs baseline: 1.3032x; 1.0367x over previous
//
#include <hip/hip_runtime.h>

typedef unsigned short u16;
typedef __bf16 bf16x8 __attribute__((ext_vector_type(8)));
typedef float f32x4 __attribute__((ext_vector_type(4)));

// fp32 -> bf16 bits, round-to-nearest-even (finite inputs only)
__device__ __forceinline__ u16 f2bf(float f) {
  union { float f; unsigned u; } v; v.f = f;
  return (u16)((v.u + 0x7fffu + ((v.u >> 16) & 1u)) >> 16);
}
__device__ __forceinline__ float bf2f(u16 h) {
  union { unsigned u; float f; } v; v.u = ((unsigned)h) << 16;
  return v.f;
}

// pack two fp32 -> bf16x2 dword (round-half-up), low = lo, high = hi
__device__ __forceinline__ unsigned pkbf(float lo, float hi) {
  union { float f; unsigned u; } a, b; a.f = lo; b.f = hi;
  return __builtin_amdgcn_perm(b.u + 0x8000u, a.u + 0x8000u, 0x07060302u);
}

__device__ __forceinline__ float fexp2(float x) {
#if __has_builtin(__builtin_amdgcn_exp2f)
  return __builtin_amdgcn_exp2f(x);
#else
  return exp2f(x);
#endif
}

// async global->LDS, 16B per lane; LDS dst = base + lane*16 (wave-uniform base)
__device__ __forceinline__ void gld16(const u16* g, u16* l) {
  __builtin_amdgcn_global_load_lds(
      (const __attribute__((address_space(1))) void*)g,
      (__attribute__((address_space(3))) void*)l, 16, 0, 0);
}

// pi permutation of a key k in [0,64) -> position in vT 64-block / P^T k-slot:
// pos = (k&32) + ((k>>2)&3)*8 + ((k>>4)&1)*4 + (k&3)

// ---------------------------------------------------------------------------
// fp32 -> bf16 bulk convert for all three inputs in ONE dispatch.
// ---------------------------------------------------------------------------
__global__ __launch_bounds__(256) void cvt3(
    const float* __restrict__ x, const float* __restrict__ wa,
    const float* __restrict__ wp, u16* __restrict__ xb,
    u16* __restrict__ wab, u16* __restrict__ wpb)
{
  int b = blockIdx.x;
  const float* in; u16* out; int i;
  if (b < 2048)      { in = x;  out = xb;  i = b * 256 + threadIdx.x; }
  else if (b < 3584) { in = wa; out = wab; i = (b - 2048) * 256 + threadIdx.x; }
  else               { in = wp; out = wpb; i = (b - 3584) * 256 + threadIdx.x; }
  const float* p = in + (size_t)i * 8;
  float4 a = *(const float4*)p, c = *(const float4*)(p + 4);
  uint4 o;
  o.x = pkbf(a.x, a.y); o.y = pkbf(a.z, a.w);
  o.z = pkbf(c.x, c.y); o.w = pkbf(c.z, c.w);
  *(uint4*)&out[(size_t)i * 8] = o;
}

// ---------------------------------------------------------------------------
// combine: y = (O0 + O1) / (l0 + l1).  O* are bf16 unnormalized partials
// [4096][1024]; l* are fp32 [4096][16] (per row,head). 8 elems/thread.
// ---------------------------------------------------------------------------
__global__ __launch_bounds__(256) void combine2(
    const u16* __restrict__ O0, const u16* __restrict__ O1,
    const float* __restrict__ l0, const float* __restrict__ l1,
    u16* __restrict__ y)
{
  int i = blockIdx.x * 256 + threadIdx.x;          // 524288 threads
  int e0 = i * 8;
  int row = e0 >> 10, h = (e0 & 1023) >> 6;
  float inv = 1.0f / (l0[row * 16 + h] + l1[row * 16 + h]);
  uint4 a = *(const uint4*)&O0[(size_t)e0];
  uint4 b = *(const uint4*)&O1[(size_t)e0];
  unsigned aw[4] = {a.x, a.y, a.z, a.w}, bw[4] = {b.x, b.y, b.z, b.w};
  uint4 o;
  unsigned ow[4];
#pragma unroll
  for (int j = 0; j < 4; ++j) {
    float lo = (bf2f((u16)(aw[j] & 0xffffu)) + bf2f((u16)(bw[j] & 0xffffu))) * inv;
    float hi = (bf2f((u16)(aw[j] >> 16))     + bf2f((u16)(bw[j] >> 16)))     * inv;
    ow[j] = pkbf(lo, hi);
  }
  o.x = ow[0]; o.y = ow[1]; o.z = ow[2]; o.w = ow[3];
  *(uint4*)&y[(size_t)e0] = o;
}

// ---------------------------------------------------------------------------
// m97-style GEMM: C[M,N] = A[M,K]*B[N,K]^T, bf16 in, fp32 acc.
// VSPLIT: n0>=2048 blocks write V TRANSPOSED to C2 (vT[1024][4096]) in
// pi-permuted key order.
// ---------------------------------------------------------------------------
template<bool COUT_F32, bool VSPLIT>
__global__ __launch_bounds__(256, 3) void gemm_lds(
    const u16* __restrict__ A, const u16* __restrict__ B, void* __restrict__ C,
    u16* __restrict__ C2, int M, int N, int K, int ldc)
{
  __shared__ u16 S[9216];
  u16* As = S;
  u16* Bs = S + 4096;
  const int tid  = threadIdx.x;
  const int wave = tid >> 6, lane = tid & 63;
  const int quad = lane >> 4, ln = lane & 15;
  const int m0 = blockIdx.y * 128, n0 = blockIdx.x * 128;
  const int wm = (wave >> 1) * 64, wn = (wave & 1) * 64;

  const int srow = wave * 32 + (lane >> 2);
  const int scol = (lane & 3) * 8;

  f32x4 acc[4][4] = {};

  for (int k0 = 0; k0 < K; k0 += 32) {
    __syncthreads();
    const u16* ga = A + (size_t)(m0 + srow) * K + k0 + scol;
    const u16* gb = B + (size_t)(n0 + srow) * K + k0 + scol;
    gld16(ga,                  As + wave * 1024);
    gld16(ga + (size_t)16 * K, As + wave * 1024 + 512);
    gld16(gb,                  Bs + wave * 1024);
    gld16(gb + (size_t)16 * K, Bs + wave * 1024 + 512);
    __syncthreads();

    bf16x8 af[4], bfr[4];
#pragma unroll
    for (int i = 0; i < 4; ++i) af[i]  = *(const bf16x8*)&As[(wm + i * 16 + ln) * 32 + quad * 8];
#pragma unroll
    for (int j = 0; j < 4; ++j) bfr[j] = *(const bf16x8*)&Bs[(wn + j * 16 + ln) * 32 + quad * 8];
#pragma unroll
    for (int i = 0; i < 4; ++i)
#pragma unroll
      for (int j = 0; j < 4; ++j)
        acc[i][j] = __builtin_amdgcn_mfma_f32_16x16x32_bf16(af[i], bfr[j], acc[i][j], 0, 0, 0);
  }

  if constexpr (VSPLIT) {
    if (n0 >= 2048) {
      u16 (*Cs)[72] = (u16(*)[72])S;
      __syncthreads();
#pragma unroll
      for (int c = 0; c < 2; ++c) {
        if ((wave >> 1) == c) {
#pragma unroll
          for (int i = 0; i < 4; ++i)
#pragma unroll
            for (int j = 0; j < 4; ++j)
#pragma unroll
              for (int r = 0; r < 4; ++r) {
                int pos = (i >> 1) * 32 + quad * 8 + (i & 1) * 4 + r;  // pi(m-in-chunk)
                Cs[wn + j * 16 + ln][pos] = f2bf(acc[i][j][r]);
              }
        }
        __syncthreads();
        {
          int nl = tid >> 1, mseg = (tid & 1) * 32;
#pragma unroll
          for (int s2 = 0; s2 < 4; ++s2) {
            uint4 v4 = *(const uint4*)&Cs[nl][mseg + s2 * 8];
            *(uint4*)&C2[(size_t)(n0 - 2048 + nl) * 4096 + m0 + c * 64 + mseg + s2 * 8] = v4;
          }
        }
        __syncthreads();
      }
      return;
    }
  }

#pragma unroll
  for (int i = 0; i < 4; ++i)
#pragma unroll
    for (int j = 0; j < 4; ++j)
#pragma unroll
      for (int r = 0; r < 4; ++r) {
        int m = m0 + wm + i * 16 + quad * 4 + r;   // C/D: row = quad*4+reg
        int n = n0 + wn + j * 16 + ln;             //      col = lane&15
        if constexpr (COUT_F32)
          ((float*)C)[(size_t)m * ldc + n] = acc[i][j][r];
        else
          ((u16*)C)[(size_t)m * ldc + n] = f2bf(acc[i][j][r]);
      }
}

// ---------------------------------------------------------------------------
// R19: 128x64-tile GEMM for GEMM2 (replaces gemm_t64).
// t64 (64^2 tile) had only 4 MFMA/wave/k-step against 2 staging ops + 2
// barriers -> latency-bound (~m102's 90 TF regime). This tile doubles MFMA
// per barrier pair (8/wave/k-step, 3 gld16), acc 32 VGPR, LDS 12 KB.
// Grid (N/64, M/128) = (16,32) = 512 blocks -> 2/CU, 8 waves/CU.
// ---------------------------------------------------------------------------
template<bool COUT_F32>
__global__ __launch_bounds__(256, 4) void gemm_mn(
    const u16* __restrict__ A, const u16* __restrict__ B, void* __restrict__ C,
    int M, int N, int K, int ldc)
{
  __shared__ u16 S[6144];            // As[128][32]@0 (4096), Bs[64][32]@4096 (2048)
  u16* As = S;
  u16* Bs = S + 4096;
  const int tid  = threadIdx.x;
  const int wave = tid >> 6, lane = tid & 63;
  const int quad = lane >> 4, ln = lane & 15;
  const int m0 = blockIdx.y * 128, n0 = blockIdx.x * 64;
  const int wm = (wave >> 1) * 64, wn = (wave & 1) * 32;

  const int srow  = wave * 32 + (lane >> 2);   // A rows (2 calls: +0, +16)
  const int srowB = wave * 16 + (lane >> 2);   // B rows (1 call)
  const int scol  = (lane & 3) * 8;

  f32x4 acc[4][2] = {};

  for (int k0 = 0; k0 < K; k0 += 32) {
    __syncthreads();
    const u16* ga = A + (size_t)(m0 + srow) * K + k0 + scol;
    gld16(ga,                  As + wave * 1024);
    gld16(ga + (size_t)16 * K, As + wave * 1024 + 512);
    gld16(B + (size_t)(n0 + srowB) * K + k0 + scol, Bs + wave * 512);
    __syncthreads();

    bf16x8 af[4], bfr[2];
#pragma unroll
    for (int i = 0; i < 4; ++i) af[i]  = *(const bf16x8*)&As[(wm + i * 16 + ln) * 32 + quad * 8];
#pragma unroll
    for (int j = 0; j < 2; ++j) bfr[j] = *(const bf16x8*)&Bs[(wn + j * 16 + ln) * 32 + quad * 8];
#pragma unroll
    for (int i = 0; i < 4; ++i)
#pragma unroll
      for (int j = 0; j < 2; ++j)
        acc[i][j] = __builtin_amdgcn_mfma_f32_16x16x32_bf16(af[i], bfr[j], acc[i][j], 0, 0, 0);
  }

#pragma unroll
  for (int i = 0; i < 4; ++i)
#pragma unroll
    for (int j = 0; j < 2; ++j)
#pragma unroll
      for (int r = 0; r < 4; ++r) {
        int m = m0 + wm + i * 16 + quad * 4 + r;
        int n = n0 + wn + j * 16 + ln;
        if constexpr (COUT_F32)
          ((float*)C)[(size_t)m * ldc + n] = acc[i][j][r];
        else
          ((u16*)C)[(size_t)m * ldc + n] = f2bf(acc[i][j][r]);
      }
}

// ---------------------------------------------------------------------------
// Fallback GEMM (fp32 staging) — used only if ws_size < 40 MiB.
// ---------------------------------------------------------------------------
template<bool F32>
__device__ __forceinline__ void stage8(u16* dst, const void* base, size_t off) {
  if constexpr (F32) {
    const float* p = (const float*)base + off;
    float4 a = *(const float4*)p;
    float4 b = *(const float4*)(p + 4);
    uint4 q;
    q.x = pkbf(a.x, a.y); q.y = pkbf(a.z, a.w);
    q.z = pkbf(b.x, b.y); q.w = pkbf(b.z, b.w);
    *(uint4*)dst = q;
  } else {
    *(uint4*)dst = *(const uint4*)((const u16*)base + off);
  }
}

template<bool AF32, bool BF32, bool COUT_F32, bool VSPLIT>
__global__ __launch_bounds__(256) void gemm_bt(
    const void* __restrict__ A, const void* __restrict__ B, void* __restrict__ C,
    u16* __restrict__ C2, int M, int N, int K, int ldc)
{
  __shared__ u16 As[128][40];
  __shared__ u16 Bs[128][40];
  const int tid  = threadIdx.x;
  const int wave = tid >> 6, lane = tid & 63;
  const int quad = lane >> 4, ln = lane & 15;
  const int m0 = blockIdx.y * 128, n0 = blockIdx.x * 128;
  const int wm = (wave >> 1) * 64, wn = (wave & 1) * 64;

  f32x4 acc[4][4] = {};

  for (int k0 = 0; k0 < K; k0 += 32) {
    __syncthreads();
#pragma unroll
    for (int i = 0; i < 2; ++i) {
      int idx = tid + i * 256;
      int row = idx >> 2, seg = (idx & 3) * 8;
      stage8<AF32>(&As[row][seg], A, (size_t)(m0 + row) * K + k0 + seg);
      stage8<BF32>(&Bs[row][seg], B, (size_t)(n0 + row) * K + k0 + seg);
    }
    __syncthreads();
    bf16x8 af[4], bfr[4];
#pragma unroll
    for (int i = 0; i < 4; ++i) af[i]  = *(const bf16x8*)&As[wm + i * 16 + ln][quad * 8];
#pragma unroll
    for (int j = 0; j < 4; ++j) bfr[j] = *(const bf16x8*)&Bs[wn + j * 16 + ln][quad * 8];
#pragma unroll
    for (int i = 0; i < 4; ++i)
#pragma unroll
      for (int j = 0; j < 4; ++j)
        acc[i][j] = __builtin_amdgcn_mfma_f32_16x16x32_bf16(af[i], bfr[j], acc[i][j], 0, 0, 0);
  }

  if constexpr (VSPLIT) {
    if (n0 >= 2048) {
      __shared__ u16 Cs[128][72];
#pragma unroll
      for (int c = 0; c < 2; ++c) {
        if ((wave >> 1) == c) {
#pragma unroll
          for (int i = 0; i < 4; ++i)
#pragma unroll
            for (int j = 0; j < 4; ++j)
#pragma unroll
              for (int r = 0; r < 4; ++r) {
                int pos = (i >> 1) * 32 + quad * 8 + (i & 1) * 4 + r;
                Cs[wn + j * 16 + ln][pos] = f2bf(acc[i][j][r]);
              }
        }
        __syncthreads();
        {
          int nl = tid >> 1, mseg = (tid & 1) * 32;
#pragma unroll
          for (int s2 = 0; s2 < 4; ++s2) {
            uint4 v4 = *(const uint4*)&Cs[nl][mseg + s2 * 8];
            *(uint4*)&C2[(size_t)(n0 - 2048 + nl) * 4096 + m0 + c * 64 + mseg + s2 * 8] = v4;
          }
        }
        __syncthreads();
      }
      return;
    }
  }

#pragma unroll
  for (int i = 0; i < 4; ++i)
#pragma unroll
    for (int j = 0; j < 4; ++j)
#pragma unroll
      for (int r = 0; r < 4; ++r) {
        int m = m0 + wm + i * 16 + quad * 4 + r;
        int n = n0 + wn + j * 16 + ln;
        if constexpr (COUT_F32)
          ((float*)C)[(size_t)m * ldc + n] = acc[i][j][r];
        else
          ((u16*)C)[(size_t)m * ldc + n] = f2bf(acc[i][j][r]);
      }
}

// ---------------------------------------------------------------------------
// Causal flash attention (MFMA), fixed-base softmax (linearly decomposable),
// transposed score path (S^T = K·Q^T, in-register P^T B-frag, O^T = V^T·P^T).
//
// R19: mapping REVERTED to R15's (proven best, 52.9 us).
//  * Mapping history: R15 qt=31-(bx>>5) -> 52.9 us (occ 25%). R16 paired
//    2-job blocks + (256,2) -> 62.0 (residency capped). R17 class-balanced
//    + (256,4) -> 111 (VGPR 128 cap -> spill). R18 class-balanced + (256,3)
//    -> 56.7 (occ 22.6%, FETCH/WRITE identical to R15 -> pure packing
//    effect; both mapping theories falsified). The block->CU deal is not
//    mod-256-class; with all 1024 blocks resident there are no queue
//    dynamics -> mapping is unpredictable from here. R15's is best known.
//  * Body: launch_bounds(256,3) + '#pragma unroll 1' diet (VGPR 76, no
//    spill). DO NOT TOUCH (R16/R17 lessons).
// ---------------------------------------------------------------------------
struct StageRegs { uint4 k0, k1, v0, v1; };

__device__ __forceinline__ StageRegs attn_stage_load(
    const u16* __restrict__ qk, const u16* __restrict__ vT,
    int h, int kbase, int tid) {
  StageRegs s;
  {
    int key = tid >> 2, seg = (tid & 3) * 16;
    const u16* kp = qk + (size_t)(kbase + key) * 2048 + 1024 + h * 64 + seg;
    s.k0 = *(const uint4*)kp;
    s.k1 = *(const uint4*)(kp + 8);
  }
  {
    int kh = tid >> 7, d = (tid >> 1) & 63, sg = (tid & 1) * 16;
    const u16* vp = vT + (size_t)(h * 64 + d) * 4096 + kbase + kh * 32 + sg;
    s.v0 = *(const uint4*)vp;
    s.v1 = *(const uint4*)(vp + 8);
  }
  return s;
}

template<bool SPLIT>
__global__ __launch_bounds__(256, SPLIT ? 3 : 2) void attn_fwd(
    const u16* __restrict__ qk, const u16* __restrict__ vT,
    u16* __restrict__ out0, u16* __restrict__ out1,
    float* __restrict__ l0buf, float* __restrict__ l1buf)
{
  // plane p = hf*4 + chunk (K: d-chunk within d-half hf; V: pi-slot chunk
  // within key-half). Row stride 16B; plane stride 65*16B (bank-group rotate).
  __shared__ __align__(16) u16 Ks[2][8][65][8];
  __shared__ __align__(16) u16 Vt[2][8][65][8];

  const int tid  = threadIdx.x;
  const int wave = tid >> 6, lane = tid & 63;
  const int quad = lane >> 4, ln = lane & 15;
  const int bx = blockIdx.x;
  int qt, h, ktb, kte;
  u16* oout; float* lout;
  if constexpr (SPLIT) {
    qt = 31 - (bx >> 5);               // heavy chunks (qt+1 iters) first
    int half = (bx >> 4) & 1;
    h = bx & 15;
    ktb = half ? (qt + 1) : 0;
    kte = half ? (2 * qt + 1) : qt;
    oout = half ? out1 : out0;
    lout = half ? l1buf : l0buf;
  } else {
    qt = (bx < 256) ? (31 - (bx >> 4)) : ((bx - 256) >> 4);
    h = bx & 15;
    ktb = 0; kte = 2 * qt + 1;
    oout = out0; lout = nullptr;
  }
  const float C1 = 0.18033688f;        // 0.125 * log2(e)

  const int sq0[2] = { qt * 128 + wave * 32, qt * 128 + wave * 32 + 16 };

  bf16x8 qa[2][2];
#pragma unroll
  for (int s = 0; s < 2; ++s) {
    const u16* qrow = qk + (size_t)(sq0[s] + ln) * 2048 + h * 64;
    qa[s][0] = *(const bf16x8*)(qrow + quad * 8);
    qa[s][1] = *(const bf16x8*)(qrow + 32 + quad * 8);
  }

  bf16x8 ones;
#pragma unroll
  for (int i = 0; i < 8; ++i) ones[i] = (__bf16)1.0f;

  f32x4 o[2][4] = {};                  // O^T tiles: [strip][d-tile]; row=d, col=qrow
  f32x4 la[2] = {};                    // l accumulator (ones-MFMA); every reg = l[ln]

  StageRegs st = attn_stage_load(qk, vT, h, ktb * 64, tid);
  int b = 0;
  for (int kt = ktb; kt <= kte; ++kt, b ^= 1) {
    {
      int key = tid >> 2, seg = (tid & 3) * 16;
      int hf = seg >> 5, q0 = (seg & 31) >> 3;           // q0 in {0,2}
      *(uint4*)&Ks[b][hf * 4 + q0][key][0]     = st.k0;  // d elems seg..seg+7
      *(uint4*)&Ks[b][hf * 4 + q0 + 1][key][0] = st.k1;  // d elems seg+8..seg+15
      int vh = tid >> 7, d = (tid >> 1) & 63, sq = (tid & 1) * 2;  // slot in {0,2}
      *(uint4*)&Vt[b][vh * 4 + sq][d][0]     = st.v0;
      *(uint4*)&Vt[b][vh * 4 + sq + 1][d][0] = st.v1;
    }
    __syncthreads();
    if (kt < kte) st = attn_stage_load(qk, vT, h, (kt + 1) * 64, tid);

    bool act[2];
#pragma unroll
    for (int s = 0; s < 2; ++s) act[s] = (kt * 64 <= sq0[s] + 15);

    // two 32-key subtiles, real loop (unroll 1) to bound register pressure
#pragma unroll 1
    for (int s2 = 0; s2 < 2; ++s2) {
      bf16x8 kf[2][2], vb[4];
#pragma unroll
      for (int hf = 0; hf < 2; ++hf)
#pragma unroll
        for (int tp = 0; tp < 2; ++tp)
          kf[hf][tp] = *(const bf16x8*)&Ks[b][hf * 4 + quad][(s2 * 2 + tp) * 16 + ln][0];
#pragma unroll
      for (int dt = 0; dt < 4; ++dt)
        vb[dt] = *(const bf16x8*)&Vt[b][s2 * 4 + quad][dt * 16 + ln][0];

#pragma unroll
      for (int s = 0; s < 2; ++s) {
        if (!act[s]) continue;         // wave-uniform
        f32x4 sv[2];
#pragma unroll
        for (int tp = 0; tp < 2; ++tp) {
          f32x4 z = {0.f, 0.f, 0.f, 0.f};
          z = __builtin_amdgcn_mfma_f32_16x16x32_bf16(kf[0][tp], qa[s][0], z, 0, 0, 0);
          z = __builtin_amdgcn_mfma_f32_16x16x32_bf16(kf[1][tp], qa[s][1], z, 0, 0, 0);
          sv[tp] = z;                  // row=key=(s2*2+tp)*16+quad*4+r, col=qrow=ln
        }
        float p[2][4];                 // [tp][r]
        if (kt * 64 + 63 > sq0[s]) {   // diagonal region: per-element causal mask
          const int qr = sq0[s] + ln;
#pragma unroll
          for (int tp = 0; tp < 2; ++tp) {
            int keyb = kt * 64 + (s2 * 2 + tp) * 16 + quad * 4;
#pragma unroll
            for (int r = 0; r < 4; ++r) {
              float arg = (keyb + r > qr) ? -200.0f : fmaf(sv[tp][r], C1, -46.0f);
              p[tp][r] = fexp2(arg);
            }
          }
        } else {
#pragma unroll
          for (int tp = 0; tp < 2; ++tp)
#pragma unroll
            for (int r = 0; r < 4; ++r)
              p[tp][r] = fexp2(fmaf(sv[tp][r], C1, -46.0f));
        }
        // P^T B-frag for this key-half (H == s2): slot j<4 -> p[0][j], j>=4 -> p[1][j-4]
        bf16x8 pv;
        pv[0] = (__bf16)p[0][0]; pv[1] = (__bf16)p[0][1];
        pv[2] = (__bf16)p[0][2]; pv[3] = (__bf16)p[0][3];
        pv[4] = (__bf16)p[1][0]; pv[5] = (__bf16)p[1][1];
        pv[6] = (__bf16)p[1][2]; pv[7] = (__bf16)p[1][3];
        // l on the MFMA pipe: D[row][col] = sum_k 1 * P^T[k][col] = l[qcol],
        // replicated over all (quad, r) -> no cross-lane reduce needed.
        la[s] = __builtin_amdgcn_mfma_f32_16x16x32_bf16(ones, pv, la[s], 0, 0, 0);
#pragma unroll
        for (int dt = 0; dt < 4; ++dt)
          o[s][dt] = __builtin_amdgcn_mfma_f32_16x16x32_bf16(vb[dt], pv, o[s][dt], 0, 0, 0);
      }
    }
  }

#pragma unroll
  for (int s = 0; s < 2; ++s) {
    int rowg = sq0[s] + ln;
    float l_s = la[s][0];              // same value in every acc reg / quad
    if constexpr (SPLIT) {
      // unnormalized bf16 partial + fp32 l partial (quad 0 stores l once)
#pragma unroll
      for (int dt = 0; dt < 4; ++dt) {
        uint2 w;
        w.x = pkbf(o[s][dt][0], o[s][dt][1]);
        w.y = pkbf(o[s][dt][2], o[s][dt][3]);
        *(uint2*)&oout[(size_t)rowg * 1024 + h * 64 + dt * 16 + quad * 4] = w;
      }
      if (quad == 0) lout[rowg * 16 + h] = l_s;
    } else {
      float inv = 1.0f / l_s;
#pragma unroll
      for (int dt = 0; dt < 4; ++dt) {
        uint2 w;
        w.x = pkbf(o[s][dt][0] * inv, o[s][dt][1] * inv);
        w.y = pkbf(o[s][dt][2] * inv, o[s][dt][3] * inv);
        *(uint2*)&oout[(size_t)rowg * 1024 + h * 64 + dt * 16 + quad * 4] = w;
      }
    }
  }
}

extern "C" void kernel_launch(void* const* d_in, const int* in_sizes, int n_in,
                              void* d_out, int out_size, void* d_ws, size_t ws_size,
                              hipStream_t stream) {
  const float* x      = (const float*)d_in[0];   // [4096,1024] fp32
  const float* w_attn = (const float*)d_in[1];   // [3072,1024] fp32
  const float* w_proj = (const float*)d_in[2];   // [1024,1024] fp32

  char* ws = (char*)d_ws;
  u16* qk = (u16*)ws;                        // 16 MiB [4096][2048]
  u16* vT = (u16*)(ws + (16u << 20));        //  8 MiB [1024][4096] pi-permuted

  if (ws_size >= (size_t)(44u << 20)) {
    // Path A: key-split attention with partial combine. Peak 42.25 MiB.
    u16*   wpb = (u16*)(ws + (24u << 20));   //  2 MiB bf16 w_proj
    u16*   xb  = (u16*)(ws + (26u << 20));   //  8 MiB bf16 x       (dead after GEMM1)
    u16*   wab = (u16*)(ws + (34u << 20));   //  6 MiB bf16 w_attn  (dead after GEMM1)
    u16*   Op0 = (u16*)(ws + (26u << 20));   //  8 MiB bf16 O-partial half0 (overlays xb)
    u16*   Op1 = (u16*)(ws + (34u << 20));   //  8 MiB bf16 O-partial half1 (overlays wab + 2 MiB)
    float* l0  = (float*)(ws + (42u << 20));            // 256 KiB
    float* l1  = (float*)(ws + (42u << 20) + (256u << 10)); // 256 KiB
    u16*   y   = (u16*)ws;                   //  8 MiB, overlays qk (dead after attn)

    cvt3<<<4096, 256, 0, stream>>>(x, w_attn, w_proj, xb, wab, wpb);
    gemm_lds<false, true><<<dim3(24, 32), 256, 0, stream>>>(
        xb, wab, qk, vT, 4096, 3072, 1024, 2048);
    attn_fwd<true><<<dim3(1024), 256, 0, stream>>>(qk, vT, Op0, Op1, l0, l1);
    combine2<<<2048, 256, 0, stream>>>(Op0, Op1, l0, l1, y);
    gemm_mn<true><<<dim3(16, 32), 256, 0, stream>>>(
        y, wpb, d_out, 4096, 1024, 1024, 1024);
  } else if (ws_size >= (size_t)(40u << 20)) {
    // Path B: R11 behavior.
    u16* wpb = (u16*)(ws + (24u << 20));
    u16* xb  = (u16*)(ws + (26u << 20));
    u16* wab = (u16*)(ws + (34u << 20));
    u16* y   = (u16*)(ws + (26u << 20));

    cvt3<<<4096, 256, 0, stream>>>(x, w_attn, w_proj, xb, wab, wpb);
    gemm_lds<false, true><<<dim3(24, 32), 256, 0, stream>>>(
        xb, wab, qk, vT, 4096, 3072, 1024, 2048);
    attn_fwd<false><<<dim3(512), 256, 0, stream>>>(qk, vT, y, nullptr, nullptr, nullptr);
    gemm_mn<true><<<dim3(16, 32), 256, 0, stream>>>(
        y, wpb, d_out, 4096, 1024, 1024, 1024);
  } else {
    // Path C: fp32-staging fallback.
    u16* y = (u16*)(ws + (24u << 20));
    gemm_bt<true, true, false, true><<<dim3(24, 32), 256, 0, stream>>>(
        x, w_attn, qk, vT, 4096, 3072, 1024, 2048);
    attn_fwd<false><<<dim3(512), 256, 0, stream>>>(qk, vT, y, nullptr, nullptr, nullptr);
    gemm_bt<false, true, true, false><<<dim3(8, 32), 256, 0, stream>>>(
        y, w_proj, d_out, nullptr, 4096, 1024, 1024, 1024);
  }
}